// Round 3
// baseline (1306.492 us; speedup 1.0000x reference)
//
#include <hip/hip_runtime.h>
#include <hip/hip_bf16.h>
#include <math.h>

#define T_TOK 8192
#define HID 1024
#define IDIM 4096
#define NE 8
#define TK (T_TOK*2)

// weight pre-scales so fp8 e4m3 stays in normal range (w_proj std 0.0029 is
// subnormal in e4m3!); epilogues multiply by the inverse in fp32.
#define SF_FC   8.0f
#define SF_PROJ 64.0f

typedef __attribute__((ext_vector_type(4))) float f32x4;

// async global -> LDS, 16B per lane; LDS dest = wave-uniform base + lane*16.
__device__ __forceinline__ void gld_lds16(const void* g, void* l)
{
    __builtin_amdgcn_global_load_lds(
        (const __attribute__((address_space(1))) void*)g,
        (__attribute__((address_space(3))) void*)l, 16, 0, 0);
}

// ---------------- weight fp32 -> fp8 (scaled) ----------------
__global__ __launch_bounds__(256) void cvt8_kernel(const float* __restrict__ src,
                                                   unsigned char* __restrict__ dst,
                                                   int n4, float scale)
{
    int i = blockIdx.x * 256 + threadIdx.x;
    int stride = gridDim.x * 256;
    for (; i < n4; i += stride) {
        float4 v = ((const float4*)src)[i];
        int d = 0;
        d = __builtin_amdgcn_cvt_pk_fp8_f32(v.x * scale, v.y * scale, d, false);
        d = __builtin_amdgcn_cvt_pk_fp8_f32(v.z * scale, v.w * scale, d, true);
        ((int*)dst)[i] = d;
    }
}

// ---------------- router: logits + softmax + top2 (4 tokens/block) ----------------
__global__ __launch_bounds__(256) void router_kernel(const float* __restrict__ x,
                                                     const float* __restrict__ wg,
                                                     float* __restrict__ logits_out,
                                                     int* __restrict__ top_idx,
                                                     float* __restrict__ top_w,
                                                     int* __restrict__ counts)
{
    int wave = threadIdx.x >> 6, lane = threadIdx.x & 63;
    int t = blockIdx.x * 4 + wave;
    const float* xr = x + (size_t)t * HID;
    float acc[NE];
#pragma unroll
    for (int e = 0; e < NE; e++) acc[e] = 0.f;
    for (int h = lane; h < HID; h += 64) {
        float xv = xr[h];
#pragma unroll
        for (int e = 0; e < NE; e++) acc[e] += xv * wg[e * HID + h];
    }
#pragma unroll
    for (int e = 0; e < NE; e++)
        for (int off = 32; off > 0; off >>= 1)
            acc[e] += __shfl_down(acc[e], off, 64);
    if (lane == 0) {
        float mx = acc[0];
        for (int e = 1; e < NE; e++) mx = fmaxf(mx, acc[e]);
        float p[NE]; float s = 0.f;
        for (int e = 0; e < NE; e++) { p[e] = expf(acc[e] - mx); s += p[e]; }
        for (int e = 0; e < NE; e++) logits_out[(size_t)t * NE + e] = acc[e];
        int i1 = 0;
        for (int e = 1; e < NE; e++) if (p[e] > p[i1]) i1 = e;
        int i2 = -1;
        for (int e = 0; e < NE; e++) { if (e == i1) continue; if (i2 < 0 || p[e] > p[i2]) i2 = e; }
        float w1 = p[i1], w2 = p[i2], sw = w1 + w2;
        top_idx[t * 2] = i1; top_idx[t * 2 + 1] = i2;
        top_w[t * 2] = w1 / sw; top_w[t * 2 + 1] = w2 / sw;
        atomicAdd(&counts[i1], 1);
        atomicAdd(&counts[i2], 1);
    }
}

__global__ void scan_kernel(const int* __restrict__ counts, int* __restrict__ offsets)
{
    if (threadIdx.x == 0) {
        int s = 0;
        for (int e = 0; e < NE; e++) { offsets[e] = s; s += counts[e]; }
        offsets[NE] = s;
    }
}

__global__ __launch_bounds__(256) void scatter_kernel(const int* __restrict__ top_idx,
                                                      const float* __restrict__ top_w,
                                                      const int* __restrict__ offsets,
                                                      int* __restrict__ counts2,
                                                      int* __restrict__ expert_tok,
                                                      float* __restrict__ slot_w,
                                                      int* __restrict__ slot_of)
{
    int t = blockIdx.x * 256 + threadIdx.x;
    if (t >= T_TOK) return;
    for (int k = 0; k < 2; k++) {
        int e = top_idx[t * 2 + k];
        int pos = atomicAdd(&counts2[e], 1);
        int slot = offsets[e] + pos;
        expert_tok[slot] = t;
        slot_w[slot] = top_w[t * 2 + k];
        slot_of[t * 2 + k] = slot;
    }
}

// gather x rows -> fp8: 256 threads x 4 elements = 1024
__global__ __launch_bounds__(256) void gather_kernel(const float* __restrict__ x,
                                                     const int* __restrict__ expert_tok,
                                                     unsigned char* __restrict__ xg)
{
    int slot = blockIdx.x;
    int tok = expert_tok[slot];
    const float4* src = (const float4*)(x + (size_t)tok * HID);
    int* dst = (int*)(xg + (size_t)slot * HID);
    int h = threadIdx.x;
    float4 v = src[h];
    int d = 0;
    d = __builtin_amdgcn_cvt_pk_fp8_f32(v.x, v.y, d, false);
    d = __builtin_amdgcn_cvt_pk_fp8_f32(v.z, v.w, d, true);
    dst[h] = d;
}

// ---------------- fp8 MFMA GEMM mainloop ----------------
// A: [cnt x KDIM] fp8 (tokens, rows clamped), B: [128 x KDIM] fp8 (weights, pre-offset).
// 128x128 tile, BK=64, 256 threads = 4 waves (2x2): wave covers 64 tokens x 64 n.
// LDS tiles 128x64 fp8 (8 KB each), unpadded (global_load_lds lane layout).
// OPERAND SWAP: weight frag is the MFMA A-operand -> D row = n, col = token,
// so each lane's 4 acc regs are 4 consecutive n (vectorizable stores).
template <int KDIM>
__device__ __forceinline__ void moe_gemm_loop(const unsigned char* __restrict__ A,
                                              int m0, int cnt,
                                              const unsigned char* __restrict__ B,
                                              unsigned char* Alds, unsigned char* Blds,
                                              f32x4 (&acc)[4][4])
{
    const int tid = threadIdx.x;
    const int lane = tid & 63, wave = tid >> 6;
    const int wt = (wave & 1) * 64, wn = (wave >> 1) * 64;
    const int fm = lane & 15, q = lane >> 4;

    // loop-invariant staging addresses: wave w stages rows [32w, 32w+32) of each tile
    const int srow = wave * 32 + (lane >> 2);
    const int sbyte = (lane & 3) * 16;
    int ra0 = m0 + srow;      ra0 = (ra0 < cnt) ? ra0 : (cnt - 1);
    int ra1 = m0 + srow + 16; ra1 = (ra1 < cnt) ? ra1 : (cnt - 1);
    const unsigned char* gA0 = A + (size_t)ra0 * KDIM + sbyte;
    const unsigned char* gA1 = A + (size_t)ra1 * KDIM + sbyte;
    const unsigned char* gB0 = B + (size_t)srow * KDIM + sbyte;
    const unsigned char* gB1 = B + (size_t)(srow + 16) * KDIM + sbyte;
    unsigned char* lA0 = Alds + (wave * 32) * 64;
    unsigned char* lA1 = lA0 + 16 * 64;
    unsigned char* lB0 = Blds + (wave * 32) * 64;
    unsigned char* lB1 = lB0 + 16 * 64;

    for (int kt = 0; kt < KDIM / 64; ++kt) {
        __syncthreads();                       // prev-iter LDS consumers done
        gld_lds16(gA0, lA0); gld_lds16(gA1, lA1);
        gld_lds16(gB0, lB0); gld_lds16(gB1, lB1);
        gA0 += 64; gA1 += 64; gB0 += 64; gB1 += 64;
        __syncthreads();                       // staging drained
#pragma unroll
        for (int h = 0; h < 2; ++h) {
            long wf[4], af[4];
#pragma unroll
            for (int ni = 0; ni < 4; ni++)
                wf[ni] = *(const long*)&Blds[(wn + ni * 16 + fm) * 64 + h * 32 + q * 8];
#pragma unroll
            for (int mi = 0; mi < 4; mi++)
                af[mi] = *(const long*)&Alds[(wt + mi * 16 + fm) * 64 + h * 32 + q * 8];
#pragma unroll
            for (int mi = 0; mi < 4; mi++)
#pragma unroll
                for (int ni = 0; ni < 4; ni++)
                    acc[mi][ni] = __builtin_amdgcn_mfma_f32_16x16x32_fp8_fp8(
                        wf[ni], af[mi], acc[mi][ni], 0, 0, 0);
        }
    }
}

// ---------------- GEMM 1: ht = gelu(Xg @ w_fc^T + b_fc) -> fp8 ----------------
__global__ __launch_bounds__(256) void gemm_fc_kernel(const unsigned char* __restrict__ xg,
                                                      const unsigned char* __restrict__ wfc,
                                                      const float* __restrict__ b_fc,
                                                      const int* __restrict__ offsets,
                                                      unsigned char* __restrict__ ht)
{
    __shared__ unsigned char Alds[128 * 64];
    __shared__ unsigned char Blds[128 * 64];
    const int e = blockIdx.z;
    const int off = offsets[e];
    const int cnt = offsets[e + 1] - off;
    const int m0 = blockIdx.y * 128;
    if (m0 >= cnt) return;
    const int n0 = blockIdx.x * 128;

    f32x4 acc[4][4] = {};
    moe_gemm_loop<HID>(xg + (size_t)off * HID, m0, cnt,
                       wfc + (size_t)e * IDIM * HID + (size_t)n0 * HID, Alds, Blds, acc);

    const int tid = threadIdx.x, lane = tid & 63, wave = tid >> 6;
    const int wt = (wave & 1) * 64, wn = (wave >> 1) * 64, fm = lane & 15, q = lane >> 4;
    const float inv = 1.0f / SF_FC;
#pragma unroll
    for (int mi = 0; mi < 4; mi++) {
        int m = m0 + wt + mi * 16 + fm;          // token (D col)
        if (m >= cnt) continue;
        unsigned char* row = ht + (size_t)(off + m) * IDIM + n0 + wn;
#pragma unroll
        for (int ni = 0; ni < 4; ni++) {
            int nb = ni * 16 + q * 4;            // 4 consecutive n (D rows)
            float4 bias = *(const float4*)&b_fc[(size_t)e * IDIM + n0 + wn + nb];
            float g[4];
#pragma unroll
            for (int r = 0; r < 4; r++) {
                float v = acc[mi][ni][r] * inv + ((const float*)&bias)[r];
                g[r] = 0.5f * v * (1.0f + erff(v * 0.70710678118654752f));
            }
            int d = 0;
            d = __builtin_amdgcn_cvt_pk_fp8_f32(g[0], g[1], d, false);
            d = __builtin_amdgcn_cvt_pk_fp8_f32(g[2], g[3], d, true);
            *(int*)&row[nb] = d;
        }
    }
}

// ---------------- GEMM 2: contrib = (ht @ w_proj^T + b_proj) * gate_w -> bf16 ----------------
__global__ __launch_bounds__(256) void gemm_proj_kernel(const unsigned char* __restrict__ ht,
                                                        const unsigned char* __restrict__ wproj,
                                                        const float* __restrict__ b_proj,
                                                        const int* __restrict__ offsets,
                                                        const float* __restrict__ slot_w,
                                                        __hip_bfloat16* __restrict__ contrib)
{
    __shared__ unsigned char Alds[128 * 64];
    __shared__ unsigned char Blds[128 * 64];
    const int e = blockIdx.z;
    const int off = offsets[e];
    const int cnt = offsets[e + 1] - off;
    const int m0 = blockIdx.y * 128;
    if (m0 >= cnt) return;
    const int n0 = blockIdx.x * 128;

    f32x4 acc[4][4] = {};
    moe_gemm_loop<IDIM>(ht + (size_t)off * IDIM, m0, cnt,
                        wproj + (size_t)e * HID * IDIM + (size_t)n0 * IDIM, Alds, Blds, acc);

    const int tid = threadIdx.x, lane = tid & 63, wave = tid >> 6;
    const int wt = (wave & 1) * 64, wn = (wave >> 1) * 64, fm = lane & 15, q = lane >> 4;
    const float inv = 1.0f / SF_PROJ;
#pragma unroll
    for (int mi = 0; mi < 4; mi++) {
        int m = m0 + wt + mi * 16 + fm;          // token
        if (m >= cnt) continue;
        float sw = slot_w[off + m];
        __hip_bfloat16* row = contrib + (size_t)(off + m) * HID + n0 + wn;
#pragma unroll
        for (int ni = 0; ni < 4; ni++) {
            int nb = ni * 16 + q * 4;
            float4 bias = *(const float4*)&b_proj[(size_t)e * HID + n0 + wn + nb];
            union { __hip_bfloat16 h[4]; ushort4 u; } t;
#pragma unroll
            for (int r = 0; r < 4; r++) {
                float v = (acc[mi][ni][r] * inv + ((const float*)&bias)[r]) * sw;
                t.h[r] = __float2bfloat16(v);
            }
            *(ushort4*)&row[nb] = t.u;           // 8B store, nb%4==0 -> aligned
        }
    }
}

// ---------------- combine: out[t] = contrib[slot0] + contrib[slot1] ----------------
__global__ __launch_bounds__(256) void combine_kernel(const __hip_bfloat16* __restrict__ contrib,
                                                      const int* __restrict__ slot_of,
                                                      float* __restrict__ out)
{
    int t = blockIdx.x;
    int s0 = slot_of[t * 2], s1 = slot_of[t * 2 + 1];
    const ushort4* c0 = (const ushort4*)(contrib + (size_t)s0 * HID);
    const ushort4* c1 = (const ushort4*)(contrib + (size_t)s1 * HID);
    float4* o = (float4*)(out + (size_t)t * HID);
    int h = threadIdx.x;
    ushort4 a = c0[h], b = c1[h];
    union { unsigned u; float f; } f0, f1, f2, f3, g0, g1, g2, g3;
    f0.u = ((unsigned)a.x << 16); f1.u = ((unsigned)a.y << 16);
    f2.u = ((unsigned)a.z << 16); f3.u = ((unsigned)a.w << 16);
    g0.u = ((unsigned)b.x << 16); g1.u = ((unsigned)b.y << 16);
    g2.u = ((unsigned)b.z << 16); g3.u = ((unsigned)b.w << 16);
    float4 r;
    r.x = f0.f + g0.f; r.y = f1.f + g1.f; r.z = f2.f + g2.f; r.w = f3.f + g3.f;
    o[h] = r;
}

extern "C" void kernel_launch(void* const* d_in, const int* in_sizes, int n_in,
                              void* d_out, int out_size, void* d_ws, size_t ws_size,
                              hipStream_t stream)
{
    const float* x      = (const float*)d_in[0];
    const float* w_gate = (const float*)d_in[1];
    const float* w_fc   = (const float*)d_in[2];
    const float* b_fc   = (const float*)d_in[3];
    const float* w_proj = (const float*)d_in[4];
    const float* b_proj = (const float*)d_in[5];
    float* out = (float*)d_out;
    float* logits_out = out + (size_t)T_TOK * HID;

    char* ws = (char*)d_ws;
    const size_t WB8 = (size_t)NE * IDIM * HID;      // one fp8 weight tensor = 32 MiB
    size_t o_wfc     = 0;
    size_t o_wproj   = o_wfc + WB8;
    size_t o_xg      = o_wproj + WB8;
    size_t o_ht      = o_xg + (size_t)TK * HID;      // fp8
    size_t o_contrib = o_ht + (size_t)TK * IDIM;     // fp8
    size_t o_route   = o_contrib + (size_t)TK * HID * 2;  // bf16

    unsigned char* wfc8   = (unsigned char*)(ws + o_wfc);
    unsigned char* wproj8 = (unsigned char*)(ws + o_wproj);
    unsigned char* xg     = (unsigned char*)(ws + o_xg);
    unsigned char* ht     = (unsigned char*)(ws + o_ht);
    __hip_bfloat16* contrib = (__hip_bfloat16*)(ws + o_contrib);

    size_t ro = o_route;
    int*   top_idx    = (int*)(ws + ro);   ro += (size_t)T_TOK * 2 * 4;
    float* top_w      = (float*)(ws + ro); ro += (size_t)T_TOK * 2 * 4;
    int*   counts     = (int*)(ws + ro);   ro += NE * 4;
    int*   counts2    = (int*)(ws + ro);   ro += NE * 4;
    int*   offsets    = (int*)(ws + ro);   ro += 16 * 4;
    int*   expert_tok = (int*)(ws + ro);   ro += (size_t)TK * 4;
    float* slot_w     = (float*)(ws + ro); ro += (size_t)TK * 4;
    int*   slot_of    = (int*)(ws + ro);   ro += (size_t)T_TOK * 2 * 4;

    if (ws_size < ro) return;

    hipMemsetAsync(counts, 0, 2 * NE * sizeof(int), stream);

    const int n4 = NE * IDIM * HID / 4;
    cvt8_kernel<<<2048, 256, 0, stream>>>(w_fc, wfc8, n4, SF_FC);
    cvt8_kernel<<<2048, 256, 0, stream>>>(w_proj, wproj8, n4, SF_PROJ);

    router_kernel<<<T_TOK / 4, 256, 0, stream>>>(x, w_gate, logits_out, top_idx, top_w, counts);
    scan_kernel<<<1, 64, 0, stream>>>(counts, offsets);
    scatter_kernel<<<T_TOK / 256, 256, 0, stream>>>(top_idx, top_w, offsets, counts2,
                                                    expert_tok, slot_w, slot_of);
    gather_kernel<<<TK, 256, 0, stream>>>(x, expert_tok, xg);

    gemm_fc_kernel<<<dim3(IDIM / 128, T_TOK / 128, NE), 256, 0, stream>>>(
        xg, wfc8, b_fc, offsets, ht);
    gemm_proj_kernel<<<dim3(HID / 128, T_TOK / 128, NE), 256, 0, stream>>>(
        ht, wproj8, b_proj, offsets, slot_w, contrib);

    combine_kernel<<<T_TOK, 256, 0, stream>>>(contrib, slot_of, out);
}

// Round 4
// 1068.108 us; speedup vs baseline: 1.2232x; 1.2232x over previous
//
#include <hip/hip_runtime.h>
#include <hip/hip_bf16.h>
#include <math.h>

#define T_TOK 8192
#define HID 1024
#define IDIM 4096
#define NE 8
#define TK (T_TOK*2)

typedef __attribute__((ext_vector_type(8))) short short8;
typedef __attribute__((ext_vector_type(4))) float f32x4;

// async global -> LDS, 16B per lane; LDS dest = wave-uniform base + lane*16.
__device__ __forceinline__ void gld_lds16(const void* g, void* l)
{
    __builtin_amdgcn_global_load_lds(
        (const __attribute__((address_space(1))) void*)g,
        (__attribute__((address_space(3))) void*)l, 16, 0, 0);
}

// ---------------- weight fp32 -> bf16 ----------------
__global__ __launch_bounds__(256) void cvt_kernel(const float* __restrict__ src,
                                                  __hip_bfloat16* __restrict__ dst, int n4)
{
    int i = blockIdx.x * 256 + threadIdx.x;
    int stride = gridDim.x * 256;
    for (; i < n4; i += stride) {
        float4 v = ((const float4*)src)[i];
        union { __hip_bfloat16 h[4]; ushort4 u; } t;
        t.h[0] = __float2bfloat16(v.x);
        t.h[1] = __float2bfloat16(v.y);
        t.h[2] = __float2bfloat16(v.z);
        t.h[3] = __float2bfloat16(v.w);
        ((ushort4*)dst)[i] = t.u;
    }
}

// ---------------- router: logits + softmax + top2 (4 tokens/block) ----------------
__global__ __launch_bounds__(256) void router_kernel(const float* __restrict__ x,
                                                     const float* __restrict__ wg,
                                                     float* __restrict__ logits_out,
                                                     int* __restrict__ top_idx,
                                                     float* __restrict__ top_w,
                                                     int* __restrict__ counts)
{
    int wave = threadIdx.x >> 6, lane = threadIdx.x & 63;
    int t = blockIdx.x * 4 + wave;
    const float* xr = x + (size_t)t * HID;
    float acc[NE];
#pragma unroll
    for (int e = 0; e < NE; e++) acc[e] = 0.f;
    for (int h = lane; h < HID; h += 64) {
        float xv = xr[h];
#pragma unroll
        for (int e = 0; e < NE; e++) acc[e] += xv * wg[e * HID + h];
    }
#pragma unroll
    for (int e = 0; e < NE; e++)
        for (int off = 32; off > 0; off >>= 1)
            acc[e] += __shfl_down(acc[e], off, 64);
    if (lane == 0) {
        float mx = acc[0];
        for (int e = 1; e < NE; e++) mx = fmaxf(mx, acc[e]);
        float p[NE]; float s = 0.f;
        for (int e = 0; e < NE; e++) { p[e] = expf(acc[e] - mx); s += p[e]; }
        for (int e = 0; e < NE; e++) logits_out[(size_t)t * NE + e] = acc[e];
        int i1 = 0;
        for (int e = 1; e < NE; e++) if (p[e] > p[i1]) i1 = e;
        int i2 = -1;
        for (int e = 0; e < NE; e++) { if (e == i1) continue; if (i2 < 0 || p[e] > p[i2]) i2 = e; }
        float w1 = p[i1], w2 = p[i2], sw = w1 + w2;
        top_idx[t * 2] = i1; top_idx[t * 2 + 1] = i2;
        top_w[t * 2] = w1 / sw; top_w[t * 2 + 1] = w2 / sw;
        atomicAdd(&counts[i1], 1);
        atomicAdd(&counts[i2], 1);
    }
}

__global__ void scan_kernel(const int* __restrict__ counts, int* __restrict__ offsets)
{
    if (threadIdx.x == 0) {
        int s = 0;
        for (int e = 0; e < NE; e++) { offsets[e] = s; s += counts[e]; }
        offsets[NE] = s;
    }
}

__global__ __launch_bounds__(256) void scatter_kernel(const int* __restrict__ top_idx,
                                                      const float* __restrict__ top_w,
                                                      const int* __restrict__ offsets,
                                                      int* __restrict__ counts2,
                                                      int* __restrict__ expert_tok,
                                                      float* __restrict__ slot_w,
                                                      int* __restrict__ slot_of)
{
    int t = blockIdx.x * 256 + threadIdx.x;
    if (t >= T_TOK) return;
    for (int k = 0; k < 2; k++) {
        int e = top_idx[t * 2 + k];
        int pos = atomicAdd(&counts2[e], 1);
        int slot = offsets[e] + pos;
        expert_tok[slot] = t;
        slot_w[slot] = top_w[t * 2 + k];
        slot_of[t * 2 + k] = slot;
    }
}

// gather x rows -> bf16: 256 threads x 4 elements = 1024
__global__ __launch_bounds__(256) void gather_kernel(const float* __restrict__ x,
                                                     const int* __restrict__ expert_tok,
                                                     __hip_bfloat16* __restrict__ xg)
{
    int slot = blockIdx.x;
    int tok = expert_tok[slot];
    const float4* src = (const float4*)(x + (size_t)tok * HID);
    ushort4* dst = (ushort4*)(xg + (size_t)slot * HID);
    int h = threadIdx.x;
    float4 v = src[h];
    union { __hip_bfloat16 h4[4]; ushort4 u; } t;
    t.h4[0] = __float2bfloat16(v.x);
    t.h4[1] = __float2bfloat16(v.y);
    t.h4[2] = __float2bfloat16(v.z);
    t.h4[3] = __float2bfloat16(v.w);
    dst[h] = t.u;
}

// ---------------- bf16 MFMA GEMM mainloop, XOR-swizzled LDS ----------------
// A: [cnt x KDIM] bf16 (tokens, rows clamped), B: [128 x KDIM] bf16 (weights, pre-offset).
// 128x128 tile, BK=32, 256 threads = 4 waves (2x2). LDS tiles 128x32 bf16, unpadded
// 64B rows = 4 chunks of 16B. global_load_lds forces LDS slot = (row l>>2, chunk l&3);
// we swizzle CONTENTS: lane l fetches global chunk (l&3)^((l>>3)&3). Frag reads then
// use chunk q^((fm>>1)&3) -> per 16-lane phase each (row-parity, chunk) occurs exactly
// 2x -> max 2-way bank aliasing (free, m136). Operand swap: weights are the MFMA
// A-operand so D row = n (lane's 4 accs = 4 consecutive n -> 8B stores).
template <int KDIM>
__device__ __forceinline__ void moe_gemm_loop(const __hip_bfloat16* __restrict__ A,
                                              int m0, int cnt,
                                              const __hip_bfloat16* __restrict__ B,
                                              __hip_bfloat16* Alds, __hip_bfloat16* Blds,
                                              f32x4 (&acc)[4][4])
{
    const int tid = threadIdx.x;
    const int lane = tid & 63, wave = tid >> 6;
    const int wt = (wave & 1) * 64, wn = (wave >> 1) * 64;
    const int fm = lane & 15, q = lane >> 4;
    const int csw = (q ^ ((fm >> 1) & 3)) * 8;   // unswizzled frag chunk (elements)

    // staging: wave w stages rows [32w,32w+32); lane l -> rel row l>>2 (+16 for 2nd instr)
    const int srow = wave * 32 + (lane >> 2);
    const int cg = ((lane & 3) ^ ((lane >> 3) & 3)) * 8;  // swizzled global chunk (elements)
    int ra0 = m0 + srow;      ra0 = (ra0 < cnt) ? ra0 : (cnt - 1);
    int ra1 = m0 + srow + 16; ra1 = (ra1 < cnt) ? ra1 : (cnt - 1);
    const __hip_bfloat16* gA0 = A + (size_t)ra0 * KDIM + cg;
    const __hip_bfloat16* gA1 = A + (size_t)ra1 * KDIM + cg;
    const __hip_bfloat16* gB0 = B + (size_t)srow * KDIM + cg;
    const __hip_bfloat16* gB1 = B + (size_t)(srow + 16) * KDIM + cg;
    __hip_bfloat16* lA0 = Alds + (wave * 32) * 32;
    __hip_bfloat16* lA1 = lA0 + 16 * 32;
    __hip_bfloat16* lB0 = Blds + (wave * 32) * 32;
    __hip_bfloat16* lB1 = lB0 + 16 * 32;

    for (int kt = 0; kt < KDIM / 32; ++kt) {
        __syncthreads();                       // prev-iter LDS consumers done
        gld_lds16(gA0, lA0); gld_lds16(gA1, lA1);
        gld_lds16(gB0, lB0); gld_lds16(gB1, lB1);
        gA0 += 32; gA1 += 32; gB0 += 32; gB1 += 32;
        __syncthreads();                       // staging drained (vmcnt(0) before barrier)

        short8 tf[4], wf[4];
#pragma unroll
        for (int mi = 0; mi < 4; mi++)
            tf[mi] = *(const short8*)&Alds[(wt + mi * 16 + fm) * 32 + csw];
#pragma unroll
        for (int ni = 0; ni < 4; ni++)
            wf[ni] = *(const short8*)&Blds[(wn + ni * 16 + fm) * 32 + csw];
#pragma unroll
        for (int mi = 0; mi < 4; mi++)
#pragma unroll
            for (int ni = 0; ni < 4; ni++)
                acc[mi][ni] = __builtin_amdgcn_mfma_f32_16x16x32_bf16(
                    wf[ni], tf[mi], acc[mi][ni], 0, 0, 0);
    }
}

// ---------------- GEMM 1: ht = gelu(Xg @ w_fc^T + b_fc) -> bf16 ----------------
__global__ __launch_bounds__(256) void gemm_fc_kernel(const __hip_bfloat16* __restrict__ xg,
                                                      const __hip_bfloat16* __restrict__ wfc,
                                                      const float* __restrict__ b_fc,
                                                      const int* __restrict__ offsets,
                                                      __hip_bfloat16* __restrict__ ht)
{
    __shared__ __hip_bfloat16 Alds[128 * 32];
    __shared__ __hip_bfloat16 Blds[128 * 32];
    const int e = blockIdx.z;
    const int off = offsets[e];
    const int cnt = offsets[e + 1] - off;
    const int m0 = blockIdx.y * 128;
    if (m0 >= cnt) return;
    const int n0 = blockIdx.x * 128;

    f32x4 acc[4][4] = {};
    moe_gemm_loop<HID>(xg + (size_t)off * HID, m0, cnt,
                       wfc + (size_t)e * IDIM * HID + (size_t)n0 * HID, Alds, Blds, acc);

    const int tid = threadIdx.x, lane = tid & 63, wave = tid >> 6;
    const int wt = (wave & 1) * 64, wn = (wave >> 1) * 64, fm = lane & 15, q = lane >> 4;
#pragma unroll
    for (int mi = 0; mi < 4; mi++) {
        int m = m0 + wt + mi * 16 + fm;          // token (D col)
        if (m >= cnt) continue;
        __hip_bfloat16* row = ht + (size_t)(off + m) * IDIM + n0 + wn;
#pragma unroll
        for (int ni = 0; ni < 4; ni++) {
            int nb = ni * 16 + q * 4;            // 4 consecutive n (D rows)
            float4 bias = *(const float4*)&b_fc[(size_t)e * IDIM + n0 + wn + nb];
            union { __hip_bfloat16 h[4]; ushort4 u; } t;
#pragma unroll
            for (int r = 0; r < 4; r++) {
                float v = acc[mi][ni][r] + ((const float*)&bias)[r];
                t.h[r] = __float2bfloat16(0.5f * v * (1.0f + erff(v * 0.70710678118654752f)));
            }
            *(ushort4*)&row[nb] = t.u;           // 8B aligned store
        }
    }
}

// ---------------- GEMM 2: contrib = (ht @ w_proj^T + b_proj) * gate_w -> bf16 ----------------
// Flat grid, XCD-swizzled: blocks sharing an A-tile (the 8 nb for one (e,mb)) land on
// one XCD (ids 8 apart, consecutive slots) so ht re-reads hit that XCD's L2 (ht=134MB
// exceeds L3).
__global__ __launch_bounds__(256) void gemm_proj_kernel(const __hip_bfloat16* __restrict__ ht,
                                                        const __hip_bfloat16* __restrict__ wproj,
                                                        const float* __restrict__ b_proj,
                                                        const int* __restrict__ offsets,
                                                        const float* __restrict__ slot_w,
                                                        __hip_bfloat16* __restrict__ contrib)
{
    __shared__ __hip_bfloat16 Alds[128 * 32];
    __shared__ __hip_bfloat16 Blds[128 * 32];
    const int f = blockIdx.x;                    // 4096 flat blocks
    const int x = f & 7, j = (f >> 3) & 7, H = f >> 6;
    const int G = H * 8 + x;                     // e*64 + mb
    const int e = G >> 6, mb = G & 63, nbk = j;
    const int off = offsets[e];
    const int cnt = offsets[e + 1] - off;
    const int m0 = mb * 128;
    if (m0 >= cnt) return;
    const int n0 = nbk * 128;

    f32x4 acc[4][4] = {};
    moe_gemm_loop<IDIM>(ht + (size_t)off * IDIM, m0, cnt,
                        wproj + (size_t)e * HID * IDIM + (size_t)n0 * IDIM, Alds, Blds, acc);

    const int tid = threadIdx.x, lane = tid & 63, wave = tid >> 6;
    const int wt = (wave & 1) * 64, wn = (wave >> 1) * 64, fm = lane & 15, q = lane >> 4;
#pragma unroll
    for (int mi = 0; mi < 4; mi++) {
        int m = m0 + wt + mi * 16 + fm;          // token
        if (m >= cnt) continue;
        float sw = slot_w[off + m];
        __hip_bfloat16* row = contrib + (size_t)(off + m) * HID + n0 + wn;
#pragma unroll
        for (int ni = 0; ni < 4; ni++) {
            int nb = ni * 16 + q * 4;
            float4 bias = *(const float4*)&b_proj[(size_t)e * HID + n0 + wn + nb];
            union { __hip_bfloat16 h[4]; ushort4 u; } t;
#pragma unroll
            for (int r = 0; r < 4; r++) {
                float v = (acc[mi][ni][r] + ((const float*)&bias)[r]) * sw;
                t.h[r] = __float2bfloat16(v);
            }
            *(ushort4*)&row[nb] = t.u;
        }
    }
}

// ---------------- combine: out[t] = contrib[slot0] + contrib[slot1] ----------------
__global__ __launch_bounds__(256) void combine_kernel(const __hip_bfloat16* __restrict__ contrib,
                                                      const int* __restrict__ slot_of,
                                                      float* __restrict__ out)
{
    int t = blockIdx.x;
    int s0 = slot_of[t * 2], s1 = slot_of[t * 2 + 1];
    const ushort4* c0 = (const ushort4*)(contrib + (size_t)s0 * HID);
    const ushort4* c1 = (const ushort4*)(contrib + (size_t)s1 * HID);
    float4* o = (float4*)(out + (size_t)t * HID);
    int h = threadIdx.x;
    ushort4 a = c0[h], b = c1[h];
    union { unsigned u; float f; } f0, f1, f2, f3, g0, g1, g2, g3;
    f0.u = ((unsigned)a.x << 16); f1.u = ((unsigned)a.y << 16);
    f2.u = ((unsigned)a.z << 16); f3.u = ((unsigned)a.w << 16);
    g0.u = ((unsigned)b.x << 16); g1.u = ((unsigned)b.y << 16);
    g2.u = ((unsigned)b.z << 16); g3.u = ((unsigned)b.w << 16);
    float4 r;
    r.x = f0.f + g0.f; r.y = f1.f + g1.f; r.z = f2.f + g2.f; r.w = f3.f + g3.f;
    o[h] = r;
}

extern "C" void kernel_launch(void* const* d_in, const int* in_sizes, int n_in,
                              void* d_out, int out_size, void* d_ws, size_t ws_size,
                              hipStream_t stream)
{
    const float* x      = (const float*)d_in[0];
    const float* w_gate = (const float*)d_in[1];
    const float* w_fc   = (const float*)d_in[2];
    const float* b_fc   = (const float*)d_in[3];
    const float* w_proj = (const float*)d_in[4];
    const float* b_proj = (const float*)d_in[5];
    float* out = (float*)d_out;
    float* logits_out = out + (size_t)T_TOK * HID;

    char* ws = (char*)d_ws;
    const size_t WB = (size_t)NE * IDIM * HID * 2;   // one bf16 weight tensor = 64 MiB
    size_t o_wfc     = 0;
    size_t o_wproj   = o_wfc + WB;
    size_t o_xg      = o_wproj + WB;
    size_t o_ht      = o_xg + (size_t)TK * HID * 2;
    size_t o_contrib = o_ht + (size_t)TK * IDIM * 2;
    size_t o_route   = o_contrib + (size_t)TK * HID * 2;

    __hip_bfloat16* wfc_b   = (__hip_bfloat16*)(ws + o_wfc);
    __hip_bfloat16* wproj_b = (__hip_bfloat16*)(ws + o_wproj);
    __hip_bfloat16* xg      = (__hip_bfloat16*)(ws + o_xg);
    __hip_bfloat16* ht      = (__hip_bfloat16*)(ws + o_ht);
    __hip_bfloat16* contrib = (__hip_bfloat16*)(ws + o_contrib);

    size_t ro = o_route;
    int*   top_idx    = (int*)(ws + ro);   ro += (size_t)T_TOK * 2 * 4;
    float* top_w      = (float*)(ws + ro); ro += (size_t)T_TOK * 2 * 4;
    int*   counts     = (int*)(ws + ro);   ro += NE * 4;
    int*   counts2    = (int*)(ws + ro);   ro += NE * 4;
    int*   offsets    = (int*)(ws + ro);   ro += 16 * 4;
    int*   expert_tok = (int*)(ws + ro);   ro += (size_t)TK * 4;
    float* slot_w     = (float*)(ws + ro); ro += (size_t)TK * 4;
    int*   slot_of    = (int*)(ws + ro);   ro += (size_t)T_TOK * 2 * 4;

    if (ws_size < ro) return;

    hipMemsetAsync(counts, 0, 2 * NE * sizeof(int), stream);

    const int n4 = NE * IDIM * HID / 4;
    cvt_kernel<<<2048, 256, 0, stream>>>(w_fc, wfc_b, n4);
    cvt_kernel<<<2048, 256, 0, stream>>>(w_proj, wproj_b, n4);

    router_kernel<<<T_TOK / 4, 256, 0, stream>>>(x, w_gate, logits_out, top_idx, top_w, counts);
    scan_kernel<<<1, 64, 0, stream>>>(counts, offsets);
    scatter_kernel<<<T_TOK / 256, 256, 0, stream>>>(top_idx, top_w, offsets, counts2,
                                                    expert_tok, slot_w, slot_of);
    gather_kernel<<<TK, 256, 0, stream>>>(x, expert_tok, xg);

    gemm_fc_kernel<<<dim3(IDIM / 128, T_TOK / 128, NE), 256, 0, stream>>>(
        xg, wfc_b, b_fc, offsets, ht);
    gemm_proj_kernel<<<NE * 64 * 8, 256, 0, stream>>>(
        ht, wproj_b, b_proj, offsets, slot_w, contrib);

    combine_kernel<<<T_TOK, 256, 0, stream>>>(contrib, slot_of, out);
}